// Round 6
// baseline (106.980 us; speedup 1.0000x reference)
//
#include <hip/hip_runtime.h>

#define IN_F   512
#define OUT_F  512
#define GRID_N 8
#define BATCH  4096
#define KDIM   (IN_F * 9)        // 4608
#define SPLITK 4
#define KCHUNK (KDIM / SPLITK)   // 1152
#define BK     64
#define NT     (KCHUNK / BK)     // 18 K-tiles per block
#define BM     256
#define BN     128
#define SLOT_H ((BM + BN) * BK)  // halves per ring slot: 24576 (48 KB)

typedef __fp16 half8 __attribute__((ext_vector_type(8)));
typedef float  f32x4 __attribute__((ext_vector_type(4)));

__device__ __forceinline__ void gload16(const void* gsrc, void* ldst) {
  __builtin_amdgcn_global_load_lds(
      (__attribute__((address_space(1))) void*)(void*)gsrc,
      (__attribute__((address_space(3))) void*)ldst, 16, 0, 0);
}

// ------- prep: feature expansion Phi[b][g*512+i] + weight pack -------------
__global__ void prep_kernel(const float* __restrict__ x, const float* __restrict__ grid,
                            const float* __restrict__ sw, const float* __restrict__ ba,
                            __fp16* __restrict__ A, __fp16* __restrict__ W) {
  const int bid = blockIdx.x;
  if (bid < (BATCH * IN_F) / 256) {            // ---- feat path ----
    const int idx = bid * 256 + threadIdx.x;   // b*512 + i
    const float xn = tanhf(x[idx]);
    const int b = idx >> 9;
    const int i = idx & (IN_F - 1);
    __fp16* arow = A + (size_t)b * KDIM + i;
#pragma unroll
    for (int g = 0; g < GRID_N; ++g) {
      const float d  = fabsf(xn - grid[g]);
      const float dd = d * d;
      const float inner = 1.0f - 6.0f * dd + 6.0f * dd * d;
      const float om = 1.0f - d;
      const float outer = 2.0f * om * om * om;
      const float bas = (d < 0.5f) ? inner : ((d < 1.0f) ? outer : 0.0f);
      arow[g * IN_F] = (__fp16)bas;
    }
    arow[8 * IN_F] = (__fp16)xn;
  } else {                                     // ---- weight path ----
    const int idx = (bid - (BATCH * IN_F) / 256) * 256 + threadIdx.x;  // o*512+i
    const float* swp = sw + (size_t)idx * GRID_N;
    __fp16* wrow = W + (size_t)(idx >> 9) * KDIM + (idx & (IN_F - 1));
#pragma unroll
    for (int g = 0; g < GRID_N; ++g) wrow[g * IN_F] = (__fp16)swp[g];
    wrow[8 * IN_F] = (__fp16)(0.1f * ba[idx]);
  }
}

// ------- split-K GEMM, counted-vmcnt 3-slot ring pipeline ------------------
// 256x128 tile, 8 waves (4x2) of 64x64, BK=64, 3-slot LDS ring (144 KB,
// 1 block/CU, 2 waves/SIMD). Per tile t: s_waitcnt vmcnt(6) (tile t landed,
// tile t+1's 6 loads STAY IN FLIGHT), raw s_barrier, issue tile t+2 into
// slot (t+2)%3 (WAR-safe: its readers finished before barrier t-1), compute.
// XOR swizzle source-side + read-side (conflict-free). setprio around MFMA.
__global__ __launch_bounds__(512, 2) void gemm_kernel(const __fp16* __restrict__ A,
                                                      const __fp16* __restrict__ W,
                                                      __fp16* __restrict__ P) {
  __shared__ __align__(16) __fp16 lds[3 * SLOT_H];   // 147456 B
  const int tid  = threadIdx.x;
  const int lane = tid & 63;
  const int fr   = lane & 15;
  const int g4   = lane >> 4;
  const int wv   = tid >> 6;       // 0..7
  const int wr   = wv >> 1;        // 0..3  (64-row band of BM=256)
  const int wc   = wv & 1;         // 0..1  (64-col band of BN=128)

  const int wg   = blockIdx.x;     // 0..255; wgid&7 -> XCD = (z, n_lo)
  const int z    = wg & 3;
  const int nlo  = (wg >> 2) & 1;
  const int m    = (wg >> 3) & 15;
  const int nhi  = (wg >> 7) & 1;
  const int m0   = m * BM;
  const int n0   = (nhi * 2 + nlo) * BN;
  const int kbase = z * KCHUNK;

  // per-thread staging addresses (6 loads/tile: 4 A + 2 B)
  const __fp16* Ag[4]; int aoff[4];
  const __fp16* Bg[2]; int boff[2];
#pragma unroll
  for (int j = 0; j < 4; ++j) {
    const int c = j * 512 + tid;           // 16B-chunk id, 0..2047
    const int r = c >> 3;                  // A row 0..255
    const int cc = (c & 7) ^ (r & 7);      // pre-swizzled global chunk
    Ag[j] = A + (size_t)(m0 + r) * KDIM + kbase + cc * 8;
    aoff[j] = c * 8;                       // LDS linear (halves)
  }
#pragma unroll
  for (int j = 0; j < 2; ++j) {
    const int c = j * 512 + tid;           // 0..1023
    const int r = c >> 3;                  // B row 0..127
    const int cc = (c & 7) ^ (r & 7);
    Bg[j] = W + (size_t)(n0 + r) * KDIM + kbase + cc * 8;
    boff[j] = BM * BK + c * 8;
  }

  f32x4 acc[4][4] = {};

#define STAGE(tt, sl) do {                                                   \
    __fp16* base_ = &lds[(sl) * SLOT_H];                                     \
    const int ko_ = (tt) * BK;                                               \
    _Pragma("unroll") for (int j = 0; j < 4; ++j)                            \
      gload16(Ag[j] + ko_, base_ + aoff[j]);                                 \
    _Pragma("unroll") for (int j = 0; j < 2; ++j)                            \
      gload16(Bg[j] + ko_, base_ + boff[j]);                                 \
  } while (0)

#define COMPUTE(sl) do {                                                     \
    const __fp16* As_ = &lds[(sl) * SLOT_H];                                 \
    const __fp16* Bs_ = As_ + BM * BK;                                       \
    _Pragma("unroll") for (int ks = 0; ks < 2; ++ks) {                       \
      half8 a_[4], b_[4];                                                    \
      _Pragma("unroll") for (int mi = 0; mi < 4; ++mi) {                     \
        const int row = wr * 64 + mi * 16 + fr;                              \
        const int ch = (ks * 4 + g4) ^ (fr & 7);                             \
        a_[mi] = *(const half8*)&As_[row * BK + ch * 8];                     \
      }                                                                      \
      _Pragma("unroll") for (int ni = 0; ni < 4; ++ni) {                     \
        const int row = wc * 64 + ni * 16 + fr;                              \
        const int ch = (ks * 4 + g4) ^ (fr & 7);                             \
        b_[ni] = *(const half8*)&Bs_[row * BK + ch * 8];                     \
      }                                                                      \
      __builtin_amdgcn_s_setprio(1);                                         \
      _Pragma("unroll") for (int mi = 0; mi < 4; ++mi)                       \
        _Pragma("unroll") for (int ni = 0; ni < 4; ++ni)                     \
          acc[mi][ni] = __builtin_amdgcn_mfma_f32_16x16x32_f16(              \
              a_[mi], b_[ni], acc[mi][ni], 0, 0, 0);                         \
      __builtin_amdgcn_s_setprio(0);                                         \
    }                                                                        \
  } while (0)

  // prologue: tiles 0,1 in flight (12 loads)
  STAGE(0, 0);
  STAGE(1, 1);

  int sl = 0;                       // slot of tile t
  for (int t = 0; t < NT - 2; ++t) {
    asm volatile("s_waitcnt vmcnt(6)" ::: "memory");   // tile t landed; t+1 flying
    __builtin_amdgcn_s_barrier();
    __builtin_amdgcn_sched_barrier(0);
    int sp2 = sl + 2; if (sp2 >= 3) sp2 -= 3;
    STAGE(t + 2, sp2);
    COMPUTE(sl);
    ++sl; if (sl >= 3) sl -= 3;
  }
  // tile NT-2: nothing new to stage; tile NT-1 still flying
  asm volatile("s_waitcnt vmcnt(6)" ::: "memory");
  __builtin_amdgcn_s_barrier();
  __builtin_amdgcn_sched_barrier(0);
  COMPUTE(sl);
  ++sl; if (sl >= 3) sl -= 3;
  // tile NT-1: final drain
  asm volatile("s_waitcnt vmcnt(0)" ::: "memory");
  __builtin_amdgcn_s_barrier();
  __builtin_amdgcn_sched_barrier(0);
  COMPUTE(sl);

#undef STAGE
#undef COMPUTE

  __fp16* Pp = P + (size_t)z * (BATCH * OUT_F);
#pragma unroll
  for (int mi = 0; mi < 4; ++mi) {
#pragma unroll
    for (int ni = 0; ni < 4; ++ni) {
      const int row = m0 + wr * 64 + mi * 16 + g4 * 4;   // C/D: row=(lane>>4)*4+reg
      const int col = n0 + wc * 64 + ni * 16 + fr;       //      col=lane&15
#pragma unroll
      for (int rg = 0; rg < 4; ++rg)
        Pp[(size_t)(row + rg) * OUT_F + col] = (__fp16)acc[mi][ni][rg];
    }
  }
}

// ------- reduce 4 fp16 split-K partials ------------------------------------
__global__ void reduce_kernel(const __fp16* __restrict__ P, float* __restrict__ out) {
  const int idx = blockIdx.x * 256 + threadIdx.x;   // half8 group, 0..262143
  float s[8] = {};
#pragma unroll
  for (int zz = 0; zz < SPLITK; ++zz) {
    const half8 v = *(const half8*)&P[(size_t)zz * (BATCH * OUT_F) + (size_t)idx * 8];
#pragma unroll
    for (int e = 0; e < 8; ++e) s[e] += (float)v[e];
  }
  f32x4 lo = {s[0], s[1], s[2], s[3]};
  f32x4 hi = {s[4], s[5], s[6], s[7]};
  ((f32x4*)out)[idx * 2]     = lo;
  ((f32x4*)out)[idx * 2 + 1] = hi;
}

extern "C" void kernel_launch(void* const* d_in, const int* in_sizes, int n_in,
                              void* d_out, int out_size, void* d_ws, size_t ws_size,
                              hipStream_t stream) {
  const float* x  = (const float*)d_in[0];
  const float* sw = (const float*)d_in[1];
  const float* ba = (const float*)d_in[2];
  const float* gp = (const float*)d_in[3];
  float* out = (float*)d_out;

  char* ws = (char*)d_ws;
  const size_t A_BYTES = (size_t)BATCH * KDIM * 2;   // 37,748,736
  const size_t W_BYTES = (size_t)OUT_F * KDIM * 2;   //  4,718,592
  __fp16* A = (__fp16*)ws;
  __fp16* W = (__fp16*)(ws + A_BYTES);
  __fp16* P = (__fp16*)(ws + A_BYTES + W_BYTES);     // 4 x 4 MB fp16 partials

  const int FEAT_BLKS = (BATCH * IN_F) / 256;        // 8192
  const int WT_BLKS   = (OUT_F * IN_F) / 256;        // 1024
  prep_kernel<<<FEAT_BLKS + WT_BLKS, 256, 0, stream>>>(x, gp, sw, ba, A, W);
  gemm_kernel<<<(BATCH / BM) * (OUT_F / BN) * SPLITK, 512, 0, stream>>>(A, W, P);
  reduce_kernel<<<(BATCH * OUT_F) / 8 / 256, 256, 0, stream>>>(P, out);
}